// Round 4
// baseline (331.579 us; speedup 1.0000x reference)
//
#include <hip/hip_runtime.h>
#include <hip/hip_bf16.h>

#define BB   16
#define CCH  256
#define DQK  32
#define NTOK 4096

typedef __attribute__((ext_vector_type(8)))  short short8;
typedef __attribute__((ext_vector_type(4)))  float f32x4;
typedef __attribute__((ext_vector_type(16))) float f32x16;
typedef unsigned short u16t;
typedef unsigned int   u32t;

__device__ __forceinline__ u16t f2bf(float f){
  u32t u = __builtin_bit_cast(u32t, f);
  u += 0x7FFFu + ((u >> 16) & 1u);
  return (u16t)(u >> 16);
}
__device__ __forceinline__ u32t pk2(float a, float b){
  return (u32t)f2bf(a) | ((u32t)f2bf(b) << 16);
}
__device__ __forceinline__ void gload16(const void* g, void* l){
  __builtin_amdgcn_global_load_lds(
      (const __attribute__((address_space(1))) void*)g,
      (__attribute__((address_space(3))) void*)l, 16, 0, 0);
}
__device__ __forceinline__ f32x16 zero16(){
  f32x16 z;
  #pragma unroll
  for (int i = 0; i < 16; ++i) z[i] = 0.f;
  return z;
}

// ---------------- Kernel 0: x [B][C][N] f32 -> xT [B][N][C] bf16 ----------------
__global__ __launch_bounds__(256) void k_xpose(const float* __restrict__ x,
                                               u16t* __restrict__ xT){
  __shared__ u16t tile[64][66];
  const int b = blockIdx.z, c0 = blockIdx.y * 64, n0 = blockIdx.x * 64;
  const int t = threadIdx.x;
  const int cg = t & 15, r0 = t >> 4;
  const float* xb = x + ((size_t)b * CCH + c0) * NTOK + n0;
  #pragma unroll
  for (int p = 0; p < 4; ++p){
    const int r = r0 + p * 16;
    float4 v = *(const float4*)(xb + (size_t)r * NTOK + cg * 4);
    tile[r][cg*4+0] = f2bf(v.x);
    tile[r][cg*4+1] = f2bf(v.y);
    tile[r][cg*4+2] = f2bf(v.z);
    tile[r][cg*4+3] = f2bf(v.w);
  }
  __syncthreads();
  const int nl = t >> 2, cc = (t & 3) * 16;
  u32t u[8];
  #pragma unroll
  for (int i = 0; i < 8; ++i)
    u[i] = (u32t)tile[cc + 2*i][nl] | ((u32t)tile[cc + 2*i + 1][nl] << 16);
  u16t* o = xT + ((size_t)b * NTOK + n0 + nl) * CCH + c0 + cc;
  *(uint4*)(o)     = make_uint4(u[0], u[1], u[2], u[3]);
  *(uint4*)(o + 8) = make_uint4(u[4], u[5], u[6], u[7]);
}

// ---------------- Kernel 1: projections Q,K [B][N][32], V [B][C][N] (bf16) ------
// Q is pre-scaled by log2(e) so attention softmax can use exp2.
__global__ __launch_bounds__(256) void k_proj(const u16t* __restrict__ xT,
    const float* __restrict__ Wq, const float* __restrict__ bq,
    const float* __restrict__ Wk, const float* __restrict__ bk,
    const float* __restrict__ Wv, const float* __restrict__ bv,
    u16t* __restrict__ Q, u16t* __restrict__ K, u16t* __restrict__ V){
  const int b = blockIdx.z, ot = blockIdx.y, nb = blockIdx.x * 64;
  const int tid = threadIdx.x;
  const int w = tid >> 6, lane = tid & 63;
  const int lo = lane & 15, g = lane >> 4;
  const float* W; const float* bias; int ob; int mode;
  if (ot == 0){
    if (w < 2){ W = Wq; bias = bq; ob = w * 16;       mode = 0; }
    else      { W = Wk; bias = bk; ob = (w - 2) * 16; mode = 1; }
  } else {      W = Wv; bias = bv; ob = (ot - 1) * 64 + w * 16; mode = 2; }

  f32x4 acc[4];
  #pragma unroll
  for (int s = 0; s < 4; ++s) acc[s] = (f32x4){0.f, 0.f, 0.f, 0.f};

  const u16t* xb = xT + ((size_t)b * NTOK + nb) * CCH;
  for (int kc = 0; kc < CCH; kc += 32){
    const float* wr = W + (size_t)(ob + lo) * CCH + kc + g * 8;
    float4 a0 = *(const float4*)wr;
    float4 a1 = *(const float4*)(wr + 4);
    short8 af;
    af[0] = (short)f2bf(a0.x); af[1] = (short)f2bf(a0.y);
    af[2] = (short)f2bf(a0.z); af[3] = (short)f2bf(a0.w);
    af[4] = (short)f2bf(a1.x); af[5] = (short)f2bf(a1.y);
    af[6] = (short)f2bf(a1.z); af[7] = (short)f2bf(a1.w);
    #pragma unroll
    for (int s = 0; s < 4; ++s){
      short8 bf = *(const short8*)(xb + (size_t)(s * 16 + lo) * CCH + kc + g * 8);
      acc[s] = __builtin_amdgcn_mfma_f32_16x16x32_bf16(af, bf, acc[s], 0, 0, 0);
    }
  }
  #pragma unroll
  for (int s = 0; s < 4; ++s){
    #pragma unroll
    for (int r = 0; r < 4; ++r){
      const int o = ob + 4 * g + r;
      const int n = nb + s * 16 + lo;
      float val = acc[s][r] + bias[o];
      if (mode == 0) val *= 1.44269504088896f;      // log2(e): exp2-domain scores
      const u16t h = f2bf(val);
      if (mode == 0)      Q[((size_t)b * NTOK + n) * DQK + o] = h;
      else if (mode == 1) K[((size_t)b * NTOK + n) * DQK + o] = h;
      else                V[((size_t)b * CCH + o) * NTOK + n] = h;
    }
  }
}

// ---------------- Kernel 2: flash attention + epilogue ----------------
// grid 512, block 256 (4 waves). Wave owns 32 queries via 32x32x16 MFMA.
// V tile [256 c][64 j] XOR-swizzled; K tile staged in MFMA-FRAGMENT ORDER
// (frag f at f*1KB + lane*16B -> linear lane*16 reads, conflict-free).
// Softmax in exp2 domain (Q pre-scaled). setprio(1) around MFMA clusters.
__global__ __launch_bounds__(256, 2) void k_attn(
    const u16t* __restrict__ Q, const u16t* __restrict__ K, const u16t* __restrict__ V,
    const float* __restrict__ x, const float* __restrict__ gamma,
    float* __restrict__ out){
  __shared__ __align__(16) u16t Vt[2][CCH * 64];   // 2 x 32 KB
  __shared__ __align__(16) u16t Kt[2][4 * 512];    // 2 x 4 KB, fragment-order
  const int bid = blockIdx.x;
  const int b  = ((bid & 7) << 1) | ((bid >> 3) & 1);
  const int qt = bid >> 4;                  // 0..31
  const int tid = threadIdx.x, w = tid >> 6, lane = tid & 63;
  const int ql = lane & 31, hi = lane >> 5;
  const int qg = qt * 128 + w * 32;         // wave's query base

  const u16t* Qb = Q + (size_t)b * NTOK * DQK;
  const u16t* Kb = K + (size_t)b * NTOK * DQK;
  const u16t* Vb = V + (size_t)b * CCH * NTOK;

  // Q fragments (B-operand, hoisted): k = d, n = q
  const short8 qf0 = *(const short8*)(Qb + (size_t)(qg + ql) * DQK + hi * 8);
  const short8 qf1 = *(const short8*)(Qb + (size_t)(qg + ql) * DQK + 16 + hi * 8);

  f32x16 acc[8];
  #pragma unroll
  for (int c = 0; c < 8; ++c) acc[c] = zero16();
  float m = -INFINITY, l = 0.f;

  // V staging lane constants (pre-swizzled global source, linear LDS dest)
  const int vrow0 = w * 64 + (lane >> 3);
  const int jsrc  = ((lane & 7) ^ (lane >> 3)) * 8;
  // K fragment-order staging: wave w stages frag w.
  //   frag f, lane l  <-  K[jb + (f&1)*32 + (l&31)][(f>>1)*16 + (l>>5)*8 ..+8]
  const size_t ksrc = (size_t)((w & 1) * 32 + ql) * DQK + (w >> 1) * 16 + hi * 8;

  // prologue: stage tile 0
  #pragma unroll
  for (int i = 0; i < 8; ++i)
    gload16(Vb + (size_t)(vrow0 + i * 8) * NTOK + jsrc,
            &Vt[0][w * 4096 + i * 512]);
  gload16(Kb + ksrc, &Kt[0][w * 512]);
  __syncthreads();

  for (int t = 0; t < 64; ++t){
    const int cur = t & 1;
    if (t < 63){
      const int jb2 = (t + 1) * 64;
      #pragma unroll
      for (int i = 0; i < 8; ++i)
        gload16(Vb + (size_t)(vrow0 + i * 8) * NTOK + jb2 + jsrc,
                &Vt[cur ^ 1][w * 4096 + i * 512]);
      gload16(Kb + (size_t)jb2 * DQK + ksrc, &Kt[cur ^ 1][w * 512]);
    }

    // ---- QK^T: S'[j][q] = mfma(K, Q) ---- (fragment-order K: linear reads)
    const u16t* kb = &Kt[cur][0];
    const short8 kf00 = *(const short8*)(kb + 0 * 512 + lane * 8);
    const short8 kf10 = *(const short8*)(kb + 1 * 512 + lane * 8);
    const short8 kf01 = *(const short8*)(kb + 2 * 512 + lane * 8);
    const short8 kf11 = *(const short8*)(kb + 3 * 512 + lane * 8);
    __builtin_amdgcn_s_setprio(1);
    f32x16 s0 = __builtin_amdgcn_mfma_f32_32x32x16_bf16(kf00, qf0, zero16(), 0, 0, 0);
    s0 = __builtin_amdgcn_mfma_f32_32x32x16_bf16(kf01, qf1, s0, 0, 0, 0);
    f32x16 s1 = __builtin_amdgcn_mfma_f32_32x32x16_bf16(kf10, qf0, zero16(), 0, 0, 0);
    s1 = __builtin_amdgcn_mfma_f32_32x32x16_bf16(kf11, qf1, s1, 0, 0, 0);
    __builtin_amdgcn_s_setprio(0);

    // ---- online softmax (exp2 domain; lane owns q = ql) ----
    float tm[8];
    #pragma unroll
    for (int r = 0; r < 8; ++r)
      tm[r] = fmaxf(fmaxf(s0[r], s0[r + 8]), fmaxf(s1[r], s1[r + 8]));
    #pragma unroll
    for (int st = 4; st > 0; st >>= 1)
      #pragma unroll
      for (int r = 0; r < st; ++r) tm[r] = fmaxf(tm[r], tm[r + st]);
    float mx = fmaxf(tm[0], __shfl_xor(tm[0], 32));
    if (!__all(mx <= m + 8.0f)){           // defer-max (log2 units): P <= 2^8
      const float mnew = fmaxf(m, mx);
      const float al = exp2f(m - mnew);
      #pragma unroll
      for (int c = 0; c < 8; ++c) acc[c] = acc[c] * al;
      l *= al; m = mnew;
    }
    float e0[16], e1[16];
    float rs = 0.f;
    #pragma unroll
    for (int r = 0; r < 16; ++r){ e0[r] = exp2f(s0[r] - m); rs += e0[r]; }
    #pragma unroll
    for (int r = 0; r < 16; ++r){ e1[r] = exp2f(s1[r] - m); rs += e1[r]; }
    rs += __shfl_xor(rs, 32);
    l += rs;

    // ---- pack P -> bf16 B-fragments in-register (shfl across hi halves) ----
    u32t pf[4][4];
    #pragma unroll
    for (int js = 0; js < 2; ++js){
      #pragma unroll
      for (int t2 = 0; t2 < 2; ++t2){
        const int base = 8 * t2;
        u32t wA0, wA1, wB0, wB1;
        if (js == 0){
          wA0 = pk2(e0[base+0], e0[base+1]); wA1 = pk2(e0[base+2], e0[base+3]);
          wB0 = pk2(e0[base+4], e0[base+5]); wB1 = pk2(e0[base+6], e0[base+7]);
        } else {
          wA0 = pk2(e1[base+0], e1[base+1]); wA1 = pk2(e1[base+2], e1[base+3]);
          wB0 = pk2(e1[base+4], e1[base+5]); wB1 = pk2(e1[base+6], e1[base+7]);
        }
        const u32t g0 = __shfl_xor(hi ? wA0 : wB0, 32);
        const u32t g1 = __shfl_xor(hi ? wA1 : wB1, 32);
        const int kt = js * 2 + t2;
        pf[kt][0] = hi ? g0 : wA0;
        pf[kt][1] = hi ? g1 : wA1;
        pf[kt][2] = hi ? wB0 : g0;
        pf[kt][3] = hi ? wB1 : g1;
      }
    }

    // ---- PV: O[c][q] += V[c][j] P[j][q] ----
    const u16t* vb = &Vt[cur][0];
    __builtin_amdgcn_s_setprio(1);
    #pragma unroll
    for (int cs = 0; cs < 8; ++cs){
      const int c = cs * 32 + ql;
      #pragma unroll
      for (int kt = 0; kt < 4; ++kt){
        const int slot = (kt * 2 + hi) ^ (c & 7);
        const short8 vf = *(const short8*)(vb + (size_t)c * 64 + slot * 8);
        const short8 pb = __builtin_bit_cast(short8, *(const uint4*)&pf[kt][0]);
        acc[cs] = __builtin_amdgcn_mfma_f32_32x32x16_bf16(vf, pb, acc[cs], 0, 0, 0);
      }
    }
    __builtin_amdgcn_s_setprio(0);
    __syncthreads();   // drains gl_lds (vmcnt) -> next buffers ready
  }

  // ---- epilogue: out = gamma * O/l + x ----
  const float inv = 1.0f / l;
  const float gm = gamma[0];
  const int n = qg + ql;
  #pragma unroll
  for (int cs = 0; cs < 8; ++cs){
    #pragma unroll
    for (int r = 0; r < 16; ++r){
      const int c = cs * 32 + (r & 3) + 8 * (r >> 2) + 4 * hi;
      const size_t idx = ((size_t)b * CCH + c) * NTOK + n;
      out[idx] = gm * (acc[cs][r] * inv) + x[idx];
    }
  }
}

extern "C" void kernel_launch(void* const* d_in, const int* in_sizes, int n_in,
                              void* d_out, int out_size, void* d_ws, size_t ws_size,
                              hipStream_t stream) {
  const float* x     = (const float*)d_in[0];
  const float* Wq    = (const float*)d_in[1];
  const float* bq    = (const float*)d_in[2];
  const float* Wk    = (const float*)d_in[3];
  const float* bk    = (const float*)d_in[4];
  const float* Wv    = (const float*)d_in[5];
  const float* bv    = (const float*)d_in[6];
  const float* gamma = (const float*)d_in[7];
  float* out = (float*)d_out;

  char* ws = (char*)d_ws;
  u16t* xT = (u16t*)(ws);                      // 32 MB
  u16t* Qw = (u16t*)(ws + 33554432);           //  4 MB
  u16t* Kw = (u16t*)(ws + 37748736);           //  4 MB
  u16t* Vw = (u16t*)(ws + 41943040);           // 32 MB  (total 72 MB)

  hipLaunchKernelGGL(k_xpose, dim3(NTOK / 64, CCH / 64, BB), dim3(256), 0, stream,
                     x, xT);
  hipLaunchKernelGGL(k_proj, dim3(NTOK / 64, 5, BB), dim3(256), 0, stream,
                     xT, Wq, bq, Wk, bk, Wv, bv, Qw, Kw, Vw);
  hipLaunchKernelGGL(k_attn, dim3(512), dim3(256), 0, stream,
                     Qw, Kw, Vw, x, gamma, out);
}

// Round 5
// 324.174 us; speedup vs baseline: 1.0228x; 1.0228x over previous
//
#include <hip/hip_runtime.h>
#include <hip/hip_bf16.h>

#define BB   16
#define CCH  256
#define DQK  32
#define NTOK 4096

typedef __attribute__((ext_vector_type(8)))  short short8;
typedef __attribute__((ext_vector_type(4)))  float f32x4;
typedef __attribute__((ext_vector_type(16))) float f32x16;
typedef unsigned short u16t;
typedef unsigned int   u32t;

__device__ __forceinline__ u16t f2bf(float f){
  u32t u = __builtin_bit_cast(u32t, f);
  u += 0x7FFFu + ((u >> 16) & 1u);
  return (u16t)(u >> 16);
}
__device__ __forceinline__ u32t cvtpk(float lo, float hi_){
  u32t d;
  asm("v_cvt_pk_bf16_f32 %0, %1, %2" : "=v"(d) : "v"(lo), "v"(hi_));
  return d;
}
__device__ __forceinline__ void lane32swap(u32t& a, u32t& b){
  asm("v_permlane32_swap_b32 %0, %1" : "+v"(a), "+v"(b));
}
__device__ __forceinline__ float swapmax(float x){
  u32t a = __builtin_bit_cast(u32t, x), b = a;
  lane32swap(a, b);
  return fmaxf(__builtin_bit_cast(float, a), __builtin_bit_cast(float, b));
}
__device__ __forceinline__ float swapadd(float x){
  u32t a = __builtin_bit_cast(u32t, x), b = a;
  lane32swap(a, b);
  return __builtin_bit_cast(float, a) + __builtin_bit_cast(float, b);
}
__device__ __forceinline__ void gload16(const void* g, void* l){
  __builtin_amdgcn_global_load_lds(
      (const __attribute__((address_space(1))) void*)g,
      (__attribute__((address_space(3))) void*)l, 16, 0, 0);
}
__device__ __forceinline__ f32x16 zero16(){
  f32x16 z;
  #pragma unroll
  for (int i = 0; i < 16; ++i) z[i] = 0.f;
  return z;
}

// ---------------- Kernel 0: x [B][C][N] f32 -> xT [B][N][C] bf16 ----------------
__global__ __launch_bounds__(256) void k_xpose(const float* __restrict__ x,
                                               u16t* __restrict__ xT){
  __shared__ u16t tile[64][66];
  const int b = blockIdx.z, c0 = blockIdx.y * 64, n0 = blockIdx.x * 64;
  const int t = threadIdx.x;
  const int cg = t & 15, r0 = t >> 4;
  const float* xb = x + ((size_t)b * CCH + c0) * NTOK + n0;
  #pragma unroll
  for (int p = 0; p < 4; ++p){
    const int r = r0 + p * 16;
    float4 v = *(const float4*)(xb + (size_t)r * NTOK + cg * 4);
    tile[r][cg*4+0] = f2bf(v.x);
    tile[r][cg*4+1] = f2bf(v.y);
    tile[r][cg*4+2] = f2bf(v.z);
    tile[r][cg*4+3] = f2bf(v.w);
  }
  __syncthreads();
  const int nl = t >> 2, cc = (t & 3) * 16;
  u32t u[8];
  #pragma unroll
  for (int i = 0; i < 8; ++i)
    u[i] = (u32t)tile[cc + 2*i][nl] | ((u32t)tile[cc + 2*i + 1][nl] << 16);
  u16t* o = xT + ((size_t)b * NTOK + n0 + nl) * CCH + c0 + cc;
  *(uint4*)(o)     = make_uint4(u[0], u[1], u[2], u[3]);
  *(uint4*)(o + 8) = make_uint4(u[4], u[5], u[6], u[7]);
}

// ---------------- Kernel 1: projections Q,K [B][N][32], V [B][C][N] (bf16) ------
// Q pre-scaled by log2(e): attention softmax runs in exp2 domain.
__global__ __launch_bounds__(256) void k_proj(const u16t* __restrict__ xT,
    const float* __restrict__ Wq, const float* __restrict__ bq,
    const float* __restrict__ Wk, const float* __restrict__ bk,
    const float* __restrict__ Wv, const float* __restrict__ bv,
    u16t* __restrict__ Q, u16t* __restrict__ K, u16t* __restrict__ V){
  const int b = blockIdx.z, ot = blockIdx.y, nb = blockIdx.x * 64;
  const int tid = threadIdx.x;
  const int w = tid >> 6, lane = tid & 63;
  const int lo = lane & 15, g = lane >> 4;
  const float* W; const float* bias; int ob; int mode;
  if (ot == 0){
    if (w < 2){ W = Wq; bias = bq; ob = w * 16;       mode = 0; }
    else      { W = Wk; bias = bk; ob = (w - 2) * 16; mode = 1; }
  } else {      W = Wv; bias = bv; ob = (ot - 1) * 64 + w * 16; mode = 2; }

  f32x4 acc[4];
  #pragma unroll
  for (int s = 0; s < 4; ++s) acc[s] = (f32x4){0.f, 0.f, 0.f, 0.f};

  const u16t* xb = xT + ((size_t)b * NTOK + nb) * CCH;
  for (int kc = 0; kc < CCH; kc += 32){
    const float* wr = W + (size_t)(ob + lo) * CCH + kc + g * 8;
    float4 a0 = *(const float4*)wr;
    float4 a1 = *(const float4*)(wr + 4);
    short8 af;
    af[0] = (short)f2bf(a0.x); af[1] = (short)f2bf(a0.y);
    af[2] = (short)f2bf(a0.z); af[3] = (short)f2bf(a0.w);
    af[4] = (short)f2bf(a1.x); af[5] = (short)f2bf(a1.y);
    af[6] = (short)f2bf(a1.z); af[7] = (short)f2bf(a1.w);
    #pragma unroll
    for (int s = 0; s < 4; ++s){
      short8 bf = *(const short8*)(xb + (size_t)(s * 16 + lo) * CCH + kc + g * 8);
      acc[s] = __builtin_amdgcn_mfma_f32_16x16x32_bf16(af, bf, acc[s], 0, 0, 0);
    }
  }
  #pragma unroll
  for (int s = 0; s < 4; ++s){
    #pragma unroll
    for (int r = 0; r < 4; ++r){
      const int o = ob + 4 * g + r;
      const int n = nb + s * 16 + lo;
      float val = acc[s][r] + bias[o];
      if (mode == 0) val *= 1.44269504088896f;
      const u16t h = f2bf(val);
      if (mode == 0)      Q[((size_t)b * NTOK + n) * DQK + o] = h;
      else if (mode == 1) K[((size_t)b * NTOK + n) * DQK + o] = h;
      else                V[((size_t)b * CCH + o) * NTOK + n] = h;
    }
  }
}

// ---------------- Kernel 2: flash attention + epilogue ----------------
// grid 512, block 256 (4 waves), 2 blocks/CU. Wave owns 32 queries (32x32x16).
// Cross-iter pipeline: per iter t -> QK(t+1), stage(t+1/t+2), softmax(t+1),
// PV(t), then rescale acc by alpha(t+1). One barrier/iter. No setprio.
// All cross-lane via v_permlane32_swap_b32 (no ds_bpermute); pack via cvt_pk.
__global__ __launch_bounds__(256, 2) void k_attn(
    const u16t* __restrict__ Q, const u16t* __restrict__ K, const u16t* __restrict__ V,
    const float* __restrict__ x, const float* __restrict__ gamma,
    float* __restrict__ out){
  __shared__ __align__(16) u16t Vt[2][CCH * 64];   // 2 x 32 KB
  __shared__ __align__(16) u16t KT[3 * 2048];      // 3 x 4 KB (triple buffer)
  const int bid = blockIdx.x;
  const int b  = ((bid & 7) << 1) | ((bid >> 3) & 1);
  const int qt = bid >> 4;
  const int tid = threadIdx.x, w = tid >> 6, lane = tid & 63;
  const int ql = lane & 31, hi = lane >> 5;
  const int qg = qt * 128 + w * 32;

  const u16t* Qb = Q + (size_t)b * NTOK * DQK;
  const u16t* Kb = K + (size_t)b * NTOK * DQK;
  const u16t* Vb = V + (size_t)b * CCH * NTOK;

  const short8 qf0 = *(const short8*)(Qb + (size_t)(qg + ql) * DQK + hi * 8);
  const short8 qf1 = *(const short8*)(Qb + (size_t)(qg + ql) * DQK + 16 + hi * 8);

  f32x16 acc[8];
  #pragma unroll
  for (int c = 0; c < 8; ++c) acc[c] = zero16();
  float m = 0.f, l = 0.f;

  // V staging lane constants (pre-swizzled global source, linear LDS dest)
  const int vrow0 = w * 64 + (lane >> 3);
  const int jsrc  = ((lane & 7) ^ (lane >> 3)) * 8;
  // K fragment-order staging: wave w stages frag w.
  const size_t ksrc = (size_t)((w & 1) * 32 + ql) * DQK + (w >> 1) * 16 + hi * 8;

  // prologue: stage V(0), K(0)->slot0, K(1)->slot1
  #pragma unroll
  for (int i = 0; i < 8; ++i)
    gload16(Vb + (size_t)(vrow0 + i * 8) * NTOK + jsrc, &Vt[0][w * 4096 + i * 512]);
  gload16(Kb + ksrc,        &KT[0 * 2048 + w * 512]);
  gload16(Kb + 2048 + ksrc, &KT[1 * 2048 + w * 512]);
  __syncthreads();

  u32t pf[4][4];

  #define QK_STEP(KBASE, S0, S1) \
    { const u16t* kb_ = (KBASE); \
      const short8 kf00 = *(const short8*)(kb_ + 0 * 512 + lane * 8); \
      const short8 kf10 = *(const short8*)(kb_ + 1 * 512 + lane * 8); \
      const short8 kf01 = *(const short8*)(kb_ + 2 * 512 + lane * 8); \
      const short8 kf11 = *(const short8*)(kb_ + 3 * 512 + lane * 8); \
      S0 = __builtin_amdgcn_mfma_f32_32x32x16_bf16(kf00, qf0, zero16(), 0, 0, 0); \
      S0 = __builtin_amdgcn_mfma_f32_32x32x16_bf16(kf01, qf1, S0, 0, 0, 0); \
      S1 = __builtin_amdgcn_mfma_f32_32x32x16_bf16(kf10, qf0, zero16(), 0, 0, 0); \
      S1 = __builtin_amdgcn_mfma_f32_32x32x16_bf16(kf11, qf1, S1, 0, 0, 0); }

  #define MAXRED(S0, S1, MX) \
    { float tm[8]; \
      _Pragma("unroll") \
      for (int r = 0; r < 8; ++r) \
        tm[r] = fmaxf(fmaxf(S0[r], S0[r + 8]), fmaxf(S1[r], S1[r + 8])); \
      _Pragma("unroll") \
      for (int st = 4; st; st >>= 1) \
        _Pragma("unroll") \
        for (int r = 0; r < st; ++r) tm[r] = fmaxf(tm[r], tm[r + st]); \
      MX = swapmax(tm[0]); }

  #define EXP_RS(S0, S1) \
    { float r0 = 0.f, r1 = 0.f, r2 = 0.f, r3 = 0.f; \
      _Pragma("unroll") \
      for (int r = 0; r < 16; ++r){ S0[r] = exp2f(S0[r] - m); } \
      _Pragma("unroll") \
      for (int r = 0; r < 16; ++r){ S1[r] = exp2f(S1[r] - m); } \
      _Pragma("unroll") \
      for (int r = 0; r < 4; ++r){ \
        r0 += S0[r]; r1 += S0[r+4]; r2 += S0[r+8]; r3 += S0[r+12]; \
        r0 += S1[r]; r1 += S1[r+4]; r2 += S1[r+8]; r3 += S1[r+12]; } \
      float rs = (r0 + r1) + (r2 + r3); \
      l += swapadd(rs); }

  #define PACK_PF(S0, S1, DST) \
    { _Pragma("unroll") \
      for (int js = 0; js < 2; ++js){ \
        _Pragma("unroll") \
        for (int t2 = 0; t2 < 2; ++t2){ \
          const int kt_ = js * 2 + t2, bo = 8 * t2; \
          u32t A1, A2, B1, B2; \
          if (js == 0){ \
            A1 = cvtpk(S0[bo+0], S0[bo+1]); A2 = cvtpk(S0[bo+2], S0[bo+3]); \
            B1 = cvtpk(S0[bo+4], S0[bo+5]); B2 = cvtpk(S0[bo+6], S0[bo+7]); \
          } else { \
            A1 = cvtpk(S1[bo+0], S1[bo+1]); A2 = cvtpk(S1[bo+2], S1[bo+3]); \
            B1 = cvtpk(S1[bo+4], S1[bo+5]); B2 = cvtpk(S1[bo+6], S1[bo+7]); \
          } \
          lane32swap(A1, B1); lane32swap(A2, B2); \
          DST[kt_][0] = A1; DST[kt_][1] = A2; DST[kt_][2] = B1; DST[kt_][3] = B2; \
        } } }

  #define PV_STEP(VBUF) \
    { const u16t* vb_ = (VBUF); \
      _Pragma("unroll") \
      for (int cs = 0; cs < 8; ++cs){ \
        const int c_ = cs * 32 + ql; \
        _Pragma("unroll") \
        for (int kt_ = 0; kt_ < 4; ++kt_){ \
          const int slot_ = (kt_ * 2 + hi) ^ (ql & 7); \
          const short8 vf_ = *(const short8*)(vb_ + (size_t)c_ * 64 + slot_ * 8); \
          const short8 pb_ = __builtin_bit_cast(short8, \
              make_uint4(pf[kt_][0], pf[kt_][1], pf[kt_][2], pf[kt_][3])); \
          acc[cs] = __builtin_amdgcn_mfma_f32_32x32x16_bf16(vf_, pb_, acc[cs], 0, 0, 0); \
        } } }

  // prologue compute: tile 0
  {
    f32x16 s0, s1;
    QK_STEP(&KT[0], s0, s1);
    float mx; MAXRED(s0, s1, mx);
    m = mx; l = 0.f;
    EXP_RS(s0, s1);
    PACK_PF(s0, s1, pf);
  }

  int krd = 1, kst = 2;
  for (int t = 0; t < 63; ++t){
    const int cur = t & 1;
    // stage V(t+1), K(min(t+2,63))
    const int jb2 = (t + 1) * 64;
    #pragma unroll
    for (int i = 0; i < 8; ++i)
      gload16(Vb + (size_t)(vrow0 + i * 8) * NTOK + jb2 + jsrc,
              &Vt[cur ^ 1][w * 4096 + i * 512]);
    const int ktile = (t + 2 < 64) ? t + 2 : 63;
    gload16(Kb + (size_t)ktile * 2048 + ksrc, &KT[kst * 2048 + w * 512]);

    // QK(t+1) from triple-buffered K slot (staged 1 iter ago)
    f32x16 s0, s1;
    QK_STEP(&KT[krd * 2048], s0, s1);

    // softmax(t+1): branchless defer-max; alpha==1 when deferred
    float mx; MAXRED(s0, s1, mx);
    const int grow = !__all(mx <= m + 8.0f);
    const float mnew = grow ? fmaxf(m, mx) : m;
    const float alpha = exp2f(m - mnew);
    m = mnew; l *= alpha;
    EXP_RS(s0, s1);

    u32t pfn[4][4];
    PACK_PF(s0, s1, pfn);

    // PV(t): acc and pf both in previous-m scale (consistent)
    PV_STEP(&Vt[cur][0]);

    if (grow){
      #pragma unroll
      for (int c = 0; c < 8; ++c) acc[c] = acc[c] * alpha;
    }
    #pragma unroll
    for (int kt_ = 0; kt_ < 4; ++kt_)
      #pragma unroll
      for (int wd = 0; wd < 4; ++wd) pf[kt_][wd] = pfn[kt_][wd];

    krd = (krd == 2) ? 0 : krd + 1;
    kst = (kst == 2) ? 0 : kst + 1;
    __syncthreads();
  }
  // tail: PV(63)
  PV_STEP(&Vt[1][0]);

  // epilogue: out = gamma * O/l + x
  const float inv = 1.0f / l;
  const float gm = gamma[0];
  const int n = qg + ql;
  #pragma unroll
  for (int cs = 0; cs < 8; ++cs){
    #pragma unroll
    for (int r = 0; r < 16; ++r){
      const int c = cs * 32 + (r & 3) + 8 * (r >> 2) + 4 * hi;
      const size_t idx = ((size_t)b * CCH + c) * NTOK + n;
      out[idx] = gm * (acc[cs][r] * inv) + x[idx];
    }
  }
}

extern "C" void kernel_launch(void* const* d_in, const int* in_sizes, int n_in,
                              void* d_out, int out_size, void* d_ws, size_t ws_size,
                              hipStream_t stream) {
  const float* x     = (const float*)d_in[0];
  const float* Wq    = (const float*)d_in[1];
  const float* bq    = (const float*)d_in[2];
  const float* Wk    = (const float*)d_in[3];
  const float* bk    = (const float*)d_in[4];
  const float* Wv    = (const float*)d_in[5];
  const float* bv    = (const float*)d_in[6];
  const float* gamma = (const float*)d_in[7];
  float* out = (float*)d_out;

  char* ws = (char*)d_ws;
  u16t* xT = (u16t*)(ws);                      // 32 MB
  u16t* Qw = (u16t*)(ws + 33554432);           //  4 MB
  u16t* Kw = (u16t*)(ws + 37748736);           //  4 MB
  u16t* Vw = (u16t*)(ws + 41943040);           // 32 MB  (total 72 MB)

  hipLaunchKernelGGL(k_xpose, dim3(NTOK / 64, CCH / 64, BB), dim3(256), 0, stream,
                     x, xT);
  hipLaunchKernelGGL(k_proj, dim3(NTOK / 64, 5, BB), dim3(256), 0, stream,
                     xT, Wq, bq, Wk, bk, Wv, bv, Qw, Kw, Vw);
  hipLaunchKernelGGL(k_attn, dim3(512), dim3(256), 0, stream,
                     Qw, Kw, Vw, x, gamma, out);
}

// Round 6
// 303.579 us; speedup vs baseline: 1.0922x; 1.0678x over previous
//
#include <hip/hip_runtime.h>
#include <hip/hip_bf16.h>

#define BB   16
#define CCH  256
#define DQK  32
#define NTOK 4096

typedef __attribute__((ext_vector_type(8)))  short short8;
typedef __attribute__((ext_vector_type(4)))  float f32x4;
typedef __attribute__((ext_vector_type(16))) float f32x16;
typedef unsigned short u16t;
typedef unsigned int   u32t;

__device__ __forceinline__ u16t f2bf(float f){
  u32t u = __builtin_bit_cast(u32t, f);
  u += 0x7FFFu + ((u >> 16) & 1u);
  return (u16t)(u >> 16);
}
__device__ __forceinline__ u32t pk2(float a, float b){
  return (u32t)f2bf(a) | ((u32t)f2bf(b) << 16);
}
__device__ __forceinline__ u32t cvtpk(float lo, float hi_){
  u32t d;
  asm("v_cvt_pk_bf16_f32 %0, %1, %2" : "=v"(d) : "v"(lo), "v"(hi_));
  return d;
}
__device__ __forceinline__ void lane32swap(u32t& a, u32t& b){
  asm("v_permlane32_swap_b32 %0, %1" : "+v"(a), "+v"(b));
}
__device__ __forceinline__ float swapmax(float x){
  u32t a = __builtin_bit_cast(u32t, x), b = a;
  lane32swap(a, b);
  return fmaxf(__builtin_bit_cast(float, a), __builtin_bit_cast(float, b));
}
__device__ __forceinline__ float swapadd(float x){
  u32t a = __builtin_bit_cast(u32t, x), b = a;
  lane32swap(a, b);
  return __builtin_bit_cast(float, a) + __builtin_bit_cast(float, b);
}
__device__ __forceinline__ void gload16(const void* g, void* l){
  __builtin_amdgcn_global_load_lds(
      (const __attribute__((address_space(1))) void*)g,
      (__attribute__((address_space(3))) void*)l, 16, 0, 0);
}
__device__ __forceinline__ f32x16 zero16(){
  f32x16 z;
  #pragma unroll
  for (int i = 0; i < 16; ++i) z[i] = 0.f;
  return z;
}
#define mfma32(A, B, C) __builtin_amdgcn_mfma_f32_32x32x16_bf16((A), (B), (C), 0, 0, 0)

// ---------------- Kernel W: convert Wq|Wk|Wv f32 -> bf16 into d_out scratch ----
__global__ __launch_bounds__(256) void k_wconv(const float* __restrict__ Wq,
    const float* __restrict__ Wk, const float* __restrict__ Wv,
    u16t* __restrict__ o){
  const int base = (blockIdx.x * 256 + threadIdx.x) * 4;   // 81920 total elems
  float4 v;
  if (base < 8192)        v = *(const float4*)(Wq + base);
  else if (base < 16384)  v = *(const float4*)(Wk + base - 8192);
  else                    v = *(const float4*)(Wv + base - 16384);
  *(uint2*)(o + base) = make_uint2(pk2(v.x, v.y), pk2(v.z, v.w));
}

// ---------------- Kernel 0: x [B][C][N] f32 -> xT [B][N][C] bf16 ----------------
__global__ __launch_bounds__(256) void k_xpose(const float* __restrict__ x,
                                               u16t* __restrict__ xT){
  __shared__ u16t tile[64][66];
  const int b = blockIdx.z, c0 = blockIdx.y * 64, n0 = blockIdx.x * 64;
  const int t = threadIdx.x;
  const int cg = t & 15, r0 = t >> 4;
  const float* xb = x + ((size_t)b * CCH + c0) * NTOK + n0;
  #pragma unroll
  for (int p = 0; p < 4; ++p){
    const int r = r0 + p * 16;
    float4 v = *(const float4*)(xb + (size_t)r * NTOK + cg * 4);
    tile[r][cg*4+0] = f2bf(v.x);
    tile[r][cg*4+1] = f2bf(v.y);
    tile[r][cg*4+2] = f2bf(v.z);
    tile[r][cg*4+3] = f2bf(v.w);
  }
  __syncthreads();
  const int nl = t >> 2, cc = (t & 3) * 16;
  u32t u[8];
  #pragma unroll
  for (int i = 0; i < 8; ++i)
    u[i] = (u32t)tile[cc + 2*i][nl] | ((u32t)tile[cc + 2*i + 1][nl] << 16);
  u16t* o = xT + ((size_t)b * NTOK + n0 + nl) * CCH + c0 + cc;
  *(uint4*)(o)     = make_uint4(u[0], u[1], u[2], u[3]);
  *(uint4*)(o + 8) = make_uint4(u[4], u[5], u[6], u[7]);
}

// ---------------- Kernel 1: projections (bf16 weights) ----------------
// Wb flat bf16: Wq rows @0, Wk @8192, Wv @16384. Q scaled by log2(e).
__global__ __launch_bounds__(256) void k_proj(const u16t* __restrict__ xT,
    const u16t* __restrict__ Wb,
    const float* __restrict__ bq, const float* __restrict__ bk,
    const float* __restrict__ bv,
    u16t* __restrict__ Q, u16t* __restrict__ K, u16t* __restrict__ V){
  const int b = blockIdx.z, ot = blockIdx.y, nb = blockIdx.x * 64;
  const int tid = threadIdx.x;
  const int w = tid >> 6, lane = tid & 63;
  const int lo = lane & 15, g = lane >> 4;
  const u16t* Wrow; const float* bias; int ob; int mode;
  if (ot == 0){
    if (w < 2){ Wrow = Wb;        bias = bq; ob = w * 16;       mode = 0; }
    else      { Wrow = Wb + 8192; bias = bk; ob = (w - 2) * 16; mode = 1; }
  } else { Wrow = Wb + 16384; bias = bv; ob = (ot - 1) * 64 + w * 16; mode = 2; }
  const u16t* wp = Wrow + (size_t)(ob + lo) * CCH + g * 8;

  f32x4 acc[4];
  #pragma unroll
  for (int s = 0; s < 4; ++s) acc[s] = (f32x4){0.f, 0.f, 0.f, 0.f};

  const u16t* xb = xT + ((size_t)b * NTOK + nb) * CCH;
  #pragma unroll
  for (int kc = 0; kc < CCH; kc += 32){
    const short8 af = *(const short8*)(wp + kc);
    #pragma unroll
    for (int s = 0; s < 4; ++s){
      short8 bf = *(const short8*)(xb + (size_t)(s * 16 + lo) * CCH + kc + g * 8);
      acc[s] = __builtin_amdgcn_mfma_f32_16x16x32_bf16(af, bf, acc[s], 0, 0, 0);
    }
  }
  #pragma unroll
  for (int s = 0; s < 4; ++s){
    #pragma unroll
    for (int r = 0; r < 4; ++r){
      const int o = ob + 4 * g + r;
      const int n = nb + s * 16 + lo;
      float val = acc[s][r] + bias[o];
      if (mode == 0) val *= 1.44269504088896f;   // exp2-domain scores
      const u16t h = f2bf(val);
      if (mode == 0)      Q[((size_t)b * NTOK + n) * DQK + o] = h;
      else if (mode == 1) K[((size_t)b * NTOK + n) * DQK + o] = h;
      else                V[((size_t)b * CCH + o) * NTOK + n] = h;
    }
  }
}

// ---------------- Kernel 2: flash attention + epilogue ----------------
// grid 512, block 256 (4 waves). Wave owns 32 queries (32x32x16 MFMA).
// Static unroll-by-2: V/K double-buffered, all LDS addresses = precomputed
// VGPR + literal offset (zero per-read VALU). Order per iter: QK(t+1) ->
// MAXRED -> PV(t) [MFMA stream overlaps following softmax VALU] -> EXP ->
// PACK -> deferred rescale. One barrier/iter. exp2-domain softmax.
__global__ __launch_bounds__(256, 2) void k_attn(
    const u16t* __restrict__ Q, const u16t* __restrict__ K, const u16t* __restrict__ V,
    const float* __restrict__ x, const float* __restrict__ gamma,
    float* __restrict__ out){
  __shared__ __align__(16) u16t KT[2 * 2048];      // 8 KB (declare first: low imm)
  __shared__ __align__(16) u16t Vt[2][CCH * 64];   // 2 x 32 KB
  const int bid = blockIdx.x;
  const int b  = ((bid & 7) << 1) | ((bid >> 3) & 1);
  const int qt = bid >> 4;
  const int tid = threadIdx.x, w = tid >> 6, lane = tid & 63;
  const int ql = lane & 31, hi = lane >> 5;
  const int qg = qt * 128 + w * 32;

  const u16t* Qb = Q + (size_t)b * NTOK * DQK;
  const u16t* Kb = K + (size_t)b * NTOK * DQK;
  const u16t* Vb = V + (size_t)b * CCH * NTOK;

  const short8 qf0 = *(const short8*)(Qb + (size_t)(qg + ql) * DQK + hi * 8);
  const short8 qf1 = *(const short8*)(Qb + (size_t)(qg + ql) * DQK + 16 + hi * 8);

  f32x16 acc[8];
  #pragma unroll
  for (int c = 0; c < 8; ++c) acc[c] = zero16();
  float m = 0.f, l = 0.f;

  // ---- precomputed addresses ----
  const int vrow0 = w * 64 + (lane >> 3);
  const int jsrc  = ((lane & 7) ^ (lane >> 3)) * 8;
  const char* vsrc0 = (const char*)Vb + ((size_t)vrow0 * NTOK + jsrc) * 2;
  const size_t kse = (size_t)((w & 1) * 32 + ql) * DQK + (w >> 1) * 16 + hi * 8;
  const char* ksrc0 = (const char*)Kb + kse * 2;
  const int kla = lane * 16;                       // K ds_read addr (bytes)
  int vaddA[4], vaddB[4];                          // V ds_read addrs (bytes)
  #pragma unroll
  for (int kt = 0; kt < 4; ++kt){
    vaddA[kt] = ql * 128 + (((kt * 2 + hi) ^ (ql & 7)) * 16);
    vaddB[kt] = vaddA[kt] + 32768;
  }
  const char* ldsV = (const char*)&Vt[0][0];
  const char* ldsK = (const char*)&KT[0];
  u32t pf[4][4];

  #define MAXRED(S0, S1, MX) \
    { float tm[8]; \
      _Pragma("unroll") \
      for (int r = 0; r < 8; ++r) \
        tm[r] = fmaxf(fmaxf(S0[r], S0[r + 8]), fmaxf(S1[r], S1[r + 8])); \
      float a_ = fmaxf(fmaxf(tm[0], tm[1]), fmaxf(tm[2], tm[3])); \
      float b_ = fmaxf(fmaxf(tm[4], tm[5]), fmaxf(tm[6], tm[7])); \
      MX = swapmax(fmaxf(a_, b_)); }

  #define EXP_RS(S0, S1, RS) \
    { float r0 = 0.f, r1 = 0.f, r2 = 0.f, r3 = 0.f; \
      _Pragma("unroll") \
      for (int r = 0; r < 16; ++r){ S0[r] = exp2f(S0[r] - m); } \
      _Pragma("unroll") \
      for (int r = 0; r < 16; ++r){ S1[r] = exp2f(S1[r] - m); } \
      _Pragma("unroll") \
      for (int r = 0; r < 4; ++r){ \
        r0 += S0[r]; r1 += S0[r+4]; r2 += S0[r+8]; r3 += S0[r+12]; \
        r0 += S1[r]; r1 += S1[r+4]; r2 += S1[r+8]; r3 += S1[r+12]; } \
      RS = (r0 + r1) + (r2 + r3); }

  #define PACK_PF(S0, S1) \
    { _Pragma("unroll") \
      for (int js = 0; js < 2; ++js){ \
        _Pragma("unroll") \
        for (int t2 = 0; t2 < 2; ++t2){ \
          const int kt_ = js * 2 + t2, bo = 8 * t2; \
          u32t A1, A2, B1, B2; \
          if (js == 0){ \
            A1 = cvtpk(S0[bo+0], S0[bo+1]); A2 = cvtpk(S0[bo+2], S0[bo+3]); \
            B1 = cvtpk(S0[bo+4], S0[bo+5]); B2 = cvtpk(S0[bo+6], S0[bo+7]); \
          } else { \
            A1 = cvtpk(S1[bo+0], S1[bo+1]); A2 = cvtpk(S1[bo+2], S1[bo+3]); \
            B1 = cvtpk(S1[bo+4], S1[bo+5]); B2 = cvtpk(S1[bo+6], S1[bo+7]); \
          } \
          lane32swap(A1, B1); lane32swap(A2, B2); \
          pf[kt_][0] = A1; pf[kt_][1] = A2; pf[kt_][2] = B1; pf[kt_][3] = B2; \
        } } }

  #define PV_STEP(VRD) \
    { _Pragma("unroll") \
      for (int kt_ = 0; kt_ < 4; ++kt_){ \
        const short8 pb_ = __builtin_bit_cast(short8, \
            make_uint4(pf[kt_][0], pf[kt_][1], pf[kt_][2], pf[kt_][3])); \
        const int va_ = (VRD) ? vaddB[kt_] : vaddA[kt_]; \
        _Pragma("unroll") \
        for (int cs = 0; cs < 8; ++cs){ \
          const short8 vf_ = *(const short8*)(ldsV + va_ + cs * 4096); \
          acc[cs] = mfma32(vf_, pb_, acc[cs]); } } }

  #define QK_STEP(KRD, S0, S1) \
    { const char* kb_ = ldsK + (KRD) * 4096; \
      const short8 kf00 = *(const short8*)(kb_ + kla + 0 * 1024); \
      const short8 kf10 = *(const short8*)(kb_ + kla + 1 * 1024); \
      const short8 kf01 = *(const short8*)(kb_ + kla + 2 * 1024); \
      const short8 kf11 = *(const short8*)(kb_ + kla + 3 * 1024); \
      S0 = mfma32(kf00, qf0, zero16()); S0 = mfma32(kf01, qf1, S0); \
      S1 = mfma32(kf10, qf0, zero16()); S1 = mfma32(kf11, qf1, S1); }

  #define ABODY(T, VRD, KRD, KST) { \
      const int t128_ = ((T) + 1) * 128; \
      _Pragma("unroll") \
      for (int i = 0; i < 8; ++i) \
        gload16(vsrc0 + (size_t)i * 65536 + t128_, &Vt[(VRD)^1][w * 4096 + i * 512]); \
      { const int kt2_ = ((T) + 2 <= 63) ? (T) + 2 : 63; \
        gload16(ksrc0 + (size_t)kt2_ * 4096, &KT[(KST) * 2048 + w * 512]); } \
      f32x16 s0, s1; \
      QK_STEP(KRD, s0, s1); \
      float mx; MAXRED(s0, s1, mx); \
      const bool grow_ = !__all(mx <= m + 8.0f); \
      const float mnew_ = grow_ ? fmaxf(m, mx) : m; \
      const float alpha_ = exp2f(m - mnew_); \
      PV_STEP(VRD); \
      m = mnew_; \
      float rs_; EXP_RS(s0, s1, rs_); \
      l = l * alpha_ + swapadd(rs_); \
      PACK_PF(s0, s1); \
      if (grow_){ \
        _Pragma("unroll") \
        for (int c = 0; c < 8; ++c) acc[c] = acc[c] * alpha_; } \
      __syncthreads(); }

  // prologue: stage V(0)->buf0, K(0)->slot0, K(1)->slot1
  #pragma unroll
  for (int i = 0; i < 8; ++i)
    gload16(vsrc0 + (size_t)i * 65536, &Vt[0][w * 4096 + i * 512]);
  gload16(ksrc0,        &KT[0 * 2048 + w * 512]);
  gload16(ksrc0 + 4096, &KT[1 * 2048 + w * 512]);
  __syncthreads();

  // prologue compute: tile 0 (QK from slot0)
  {
    f32x16 s0, s1;
    QK_STEP(0, s0, s1);
    float mx; MAXRED(s0, s1, mx);
    m = mx;
    float rs_; EXP_RS(s0, s1, rs_);
    l = swapadd(rs_);
    PACK_PF(s0, s1);
  }
  __syncthreads();   // all waves done reading K slot0 before t=0 overwrites it

  for (int t = 0; t < 62; t += 2){
    ABODY(t,     0, 1, 0)
    ABODY(t + 1, 1, 0, 1)
  }
  ABODY(62, 0, 1, 0)
  PV_STEP(1)         // tail: PV(63) from buf1

  // ---- epilogue: out = gamma * O/l + x ----
  const float inv = 1.0f / l;
  const float gm = gamma[0];
  const int n = qg + ql;
  #pragma unroll
  for (int cs = 0; cs < 8; ++cs){
    #pragma unroll
    for (int r = 0; r < 16; ++r){
      const int c = cs * 32 + (r & 3) + 8 * (r >> 2) + 4 * hi;
      const size_t idx = ((size_t)b * CCH + c) * NTOK + n;
      out[idx] = gm * (acc[cs][r] * inv) + x[idx];
    }
  }
  #undef MAXRED
  #undef EXP_RS
  #undef PACK_PF
  #undef PV_STEP
  #undef QK_STEP
  #undef ABODY
}

extern "C" void kernel_launch(void* const* d_in, const int* in_sizes, int n_in,
                              void* d_out, int out_size, void* d_ws, size_t ws_size,
                              hipStream_t stream) {
  const float* x     = (const float*)d_in[0];
  const float* Wq    = (const float*)d_in[1];
  const float* bq    = (const float*)d_in[2];
  const float* Wk    = (const float*)d_in[3];
  const float* bk    = (const float*)d_in[4];
  const float* Wv    = (const float*)d_in[5];
  const float* bv    = (const float*)d_in[6];
  const float* gamma = (const float*)d_in[7];
  float* out = (float*)d_out;

  char* ws = (char*)d_ws;
  u16t* xT = (u16t*)(ws);                      // 32 MB
  u16t* Qw = (u16t*)(ws + 33554432);           //  4 MB
  u16t* Kw = (u16t*)(ws + 37748736);           //  4 MB
  u16t* Vw = (u16t*)(ws + 41943040);           // 32 MB  (total 72 MB)
  u16t* Wbf = (u16t*)d_out;                    // 160 KB scratch, overwritten by k_attn

  hipLaunchKernelGGL(k_wconv, dim3(80), dim3(256), 0, stream, Wq, Wk, Wv, Wbf);
  hipLaunchKernelGGL(k_xpose, dim3(NTOK / 64, CCH / 64, BB), dim3(256), 0, stream,
                     x, xT);
  hipLaunchKernelGGL(k_proj, dim3(NTOK / 64, 5, BB), dim3(256), 0, stream,
                     xT, Wbf, bq, bk, bv, Qw, Kw, Vw);
  hipLaunchKernelGGL(k_attn, dim3(512), dim3(256), 0, stream,
                     Qw, Kw, Vw, x, gamma, out);
}